// Round 1
// baseline (1167.510 us; speedup 1.0000x reference)
//
#include <hip/hip_runtime.h>
#include <hip/hip_bf16.h>

#define N_NODES 50000
#define N_EDGES 800000
#define E_TOT   (N_EDGES + N_NODES)   // 850000 with self-loops
#define IN_CH   128
#define HID     64
#define HEADS   4
#define OUT_CH  40
#define LAYERS  4
#define LN_EPS  1e-5f

// ---------------- CSR build (dst -> list of src), rebuilt every launch ----------------

__global__ void k_hist(const int* __restrict__ ei, int* __restrict__ cnt) {
    int e = blockIdx.x * blockDim.x + threadIdx.x;
    if (e >= E_TOT) return;
    int dst = (e < N_EDGES) ? ei[N_EDGES + e] : (e - N_EDGES);
    atomicAdd(&cnt[dst], 1);
}

__global__ __launch_bounds__(1024) void k_scan(const int* __restrict__ cnt,
                                               int* __restrict__ row_ptr,
                                               int* __restrict__ cursor) {
    __shared__ int wave_tot[16];
    __shared__ int s_carry;
    int tid = threadIdx.x, lane = tid & 63, w = tid >> 6;
    if (tid == 0) s_carry = 0;
    __syncthreads();
    for (int base = 0; base < N_NODES; base += 1024) {
        int i = base + tid;
        int v = (i < N_NODES) ? cnt[i] : 0;
        int x = v;
        // inclusive scan within wave
        for (int off = 1; off < 64; off <<= 1) {
            int t = __shfl_up(x, off, 64);
            if (lane >= off) x += t;
        }
        if (lane == 63) wave_tot[w] = x;
        __syncthreads();
        if (w == 0) {   // scan the 16 wave totals
            int t = (lane < 16) ? wave_tot[lane] : 0;
            for (int off = 1; off < 16; off <<= 1) {
                int u = __shfl_up(t, off, 64);
                if (lane >= off) t += u;
            }
            if (lane < 16) wave_tot[lane] = t;   // inclusive totals
        }
        __syncthreads();
        int wave_off = (w > 0) ? wave_tot[w - 1] : 0;
        int excl = s_carry + wave_off + x - v;
        if (i < N_NODES) { row_ptr[i] = excl; cursor[i] = excl; }
        __syncthreads();
        if (tid == 0) s_carry += wave_tot[15];
        __syncthreads();
    }
    if (threadIdx.x == 0) row_ptr[N_NODES] = s_carry;
}

__global__ void k_scatter(const int* __restrict__ ei, int* __restrict__ cursor,
                          int* __restrict__ csr_src) {
    int e = blockIdx.x * blockDim.x + threadIdx.x;
    if (e >= E_TOT) return;
    int src, dst;
    if (e < N_EDGES) { src = ei[e]; dst = ei[N_EDGES + e]; }
    else             { src = dst = e - N_EDGES; }
    int pos = atomicAdd(&cursor[dst], 1);
    csr_src[pos] = src;
}

// ---------------- layer-0 GEMM: h = elu(x @ Wi + bi), x [N,128], Wi [128,64] ----------------

__global__ __launch_bounds__(256) void k_gemm_in(const float* __restrict__ x,
                                                 const float* __restrict__ Wi,
                                                 const float* __restrict__ bi,
                                                 float* __restrict__ h) {
    __shared__ float Ws[IN_CH * HID];     // 32 KB
    __shared__ float xs[64 * IN_CH];      // 32 KB, row-major
    int tid = threadIdx.x;
    int row0 = blockIdx.x * 64;
    for (int i = tid; i < IN_CH * HID; i += 256) Ws[i] = Wi[i];
    for (int i = tid; i < 64 * IN_CH; i += 256) {
        int r = i >> 7;
        int rr = row0 + r;
        xs[i] = (rr < N_NODES) ? x[(size_t)rr * IN_CH + (i & 127)] : 0.f;
    }
    __syncthreads();
    int c = tid & 63;
    int g = tid >> 6;                 // row group 0..3 -> rows g*16..g*16+15
    float acc[16];
#pragma unroll
    for (int r = 0; r < 16; ++r) acc[r] = 0.f;
    for (int k = 0; k < IN_CH; ++k) {
        float w = Ws[k * HID + c];
        const float* xp = xs + (g * 16) * IN_CH + k;
#pragma unroll
        for (int r = 0; r < 16; ++r)
            acc[r] = fmaf(xp[r * IN_CH], w, acc[r]);   // broadcast LDS read
    }
    float bias = bi[c];
#pragma unroll
    for (int r = 0; r < 16; ++r) {
        int rr = row0 + g * 16 + r;
        if (rr < N_NODES) {
            float v = acc[r] + bias;
            h[(size_t)rr * HID + c] = v > 0.f ? v : (__expf(v) - 1.f);
        }
    }
}

// ---------------- per-layer GEMM: xl = h @ W, h [N,64], W [64,256] ----------------

__global__ __launch_bounds__(256) void k_gemm_xl(const float* __restrict__ h,
                                                 const float* __restrict__ W,
                                                 float* __restrict__ xl) {
    __shared__ float Ws[HID * 256];   // 64 KB
    __shared__ float hs[64 * HID];    // 16 KB
    int tid = threadIdx.x;
    int row0 = blockIdx.x * 64;
    for (int i = tid; i < HID * 256; i += 256) Ws[i] = W[i];
    for (int i = tid; i < 64 * HID; i += 256) {
        int r = i >> 6; int rr = row0 + r;
        hs[i] = (rr < N_NODES) ? h[(size_t)rr * HID + (i & 63)] : 0.f;
    }
    __syncthreads();
#pragma unroll
    for (int half = 0; half < 2; ++half) {
        float acc[32];
#pragma unroll
        for (int r = 0; r < 32; ++r) acc[r] = 0.f;
        for (int k = 0; k < HID; ++k) {
            float w = Ws[k * 256 + tid];
            const float* hp = hs + (half * 32) * HID + k;
#pragma unroll
            for (int r = 0; r < 32; ++r)
                acc[r] = fmaf(hp[r * HID], w, acc[r]);  // broadcast LDS read
        }
#pragma unroll
        for (int r = 0; r < 32; ++r) {
            int rr = row0 + half * 32 + r;
            if (rr < N_NODES) xl[(size_t)rr * 256 + tid] = acc[r];
        }
    }
}

// ---------------- alpha_s/alpha_d: per-node per-head dot with att vectors ----------------

__global__ __launch_bounds__(256) void k_alpha(const float* __restrict__ xl,
                                               const float* __restrict__ a_src,  // [4,64]
                                               const float* __restrict__ a_dst,
                                               float* __restrict__ alpha_s,
                                               float* __restrict__ alpha_d) {
    int lane = threadIdx.x & 63;
    int n = blockIdx.x * 4 + (threadIdx.x >> 6);
    if (n >= N_NODES) return;
    const float4 v = *(const float4*)(xl + (size_t)n * 256 + lane * 4);
    int hh = lane >> 4;          // head (16 lanes per head)
    int c0 = (lane & 15) * 4;
    const float4 as = *(const float4*)(a_src + hh * HID + c0);
    const float4 ad = *(const float4*)(a_dst + hh * HID + c0);
    float ps = v.x * as.x + v.y * as.y + v.z * as.z + v.w * as.w;
    float pd = v.x * ad.x + v.y * ad.y + v.z * ad.z + v.w * ad.w;
    for (int off = 1; off < 16; off <<= 1) {
        ps += __shfl_xor(ps, off, 64);
        pd += __shfl_xor(pd, off, 64);
    }
    if ((lane & 15) == 0) {
        alpha_s[n * 4 + hh] = ps;
        alpha_d[n * 4 + hh] = pd;
    }
}

// ---------------- fused GAT aggregate + mean-heads + bias + LN + ELU + residual ----------------
// one wave per destination node; lane = channel

__device__ __forceinline__ void edge_scores(float4 as, float4 ad,
                                            float& s0, float& s1, float& s2, float& s3) {
    s0 = as.x + ad.x; s0 = s0 > 0.f ? s0 : 0.2f * s0;
    s1 = as.y + ad.y; s1 = s1 > 0.f ? s1 : 0.2f * s1;
    s2 = as.z + ad.z; s2 = s2 > 0.f ? s2 : 0.2f * s2;
    s3 = as.w + ad.w; s3 = s3 > 0.f ? s3 : 0.2f * s3;
}

__global__ __launch_bounds__(256) void k_aggregate(
    const float* __restrict__ xl,
    const float* __restrict__ alpha_s,
    const float* __restrict__ alpha_d,
    const int* __restrict__ row_ptr,
    const int* __restrict__ csr_src,
    const float* __restrict__ gat_b,
    const float* __restrict__ ln_g,
    const float* __restrict__ ln_b,
    const float* __restrict__ h_res,
    float* __restrict__ h_out,
    int use_res)
{
    int lane = threadIdx.x & 63;
    int d = blockIdx.x * 4 + (threadIdx.x >> 6);
    if (d >= N_NODES) return;
    int start = row_ptr[d], end = row_ptr[d + 1];

    float4 ad = *(const float4*)(alpha_d + d * 4);

    // pass 1: segment max per head
    float m0 = -1e30f, m1 = -1e30f, m2 = -1e30f, m3 = -1e30f;
    for (int base = start; base < end; base += 64) {
        int idx = base + lane;
        if (idx < end) {
            int s = csr_src[idx];
            float4 as = *(const float4*)(alpha_s + s * 4);
            float s0, s1, s2, s3; edge_scores(as, ad, s0, s1, s2, s3);
            m0 = fmaxf(m0, s0); m1 = fmaxf(m1, s1);
            m2 = fmaxf(m2, s2); m3 = fmaxf(m3, s3);
        }
    }
    for (int off = 32; off; off >>= 1) {
        m0 = fmaxf(m0, __shfl_xor(m0, off, 64));
        m1 = fmaxf(m1, __shfl_xor(m1, off, 64));
        m2 = fmaxf(m2, __shfl_xor(m2, off, 64));
        m3 = fmaxf(m3, __shfl_xor(m3, off, 64));
    }

    // pass 2: denom
    float d0 = 0.f, d1 = 0.f, d2 = 0.f, d3 = 0.f;
    for (int base = start; base < end; base += 64) {
        int idx = base + lane;
        if (idx < end) {
            int s = csr_src[idx];
            float4 as = *(const float4*)(alpha_s + s * 4);
            float s0, s1, s2, s3; edge_scores(as, ad, s0, s1, s2, s3);
            d0 += __expf(s0 - m0); d1 += __expf(s1 - m1);
            d2 += __expf(s2 - m2); d3 += __expf(s3 - m3);
        }
    }
    for (int off = 32; off; off >>= 1) {
        d0 += __shfl_xor(d0, off, 64);
        d1 += __shfl_xor(d1, off, 64);
        d2 += __shfl_xor(d2, off, 64);
        d3 += __shfl_xor(d3, off, 64);
    }
    float i0 = 1.f / (d0 + 1e-16f), i1 = 1.f / (d1 + 1e-16f);
    float i2 = 1.f / (d2 + 1e-16f), i3 = 1.f / (d3 + 1e-16f);

    // pass 3: weighted gather-accumulate (lane = channel)
    float acc0 = 0.f, acc1 = 0.f, acc2 = 0.f, acc3 = 0.f;
    for (int base = start; base < end; base += 64) {
        int cnt = min(64, end - base);
        int idx = base + lane;
        int s = 0; float a0 = 0.f, a1 = 0.f, a2 = 0.f, a3 = 0.f;
        if (lane < cnt) {
            s = csr_src[idx];
            float4 as = *(const float4*)(alpha_s + s * 4);
            float s0, s1, s2, s3; edge_scores(as, ad, s0, s1, s2, s3);
            a0 = __expf(s0 - m0) * i0; a1 = __expf(s1 - m1) * i1;
            a2 = __expf(s2 - m2) * i2; a3 = __expf(s3 - m3) * i3;
        }
        for (int j = 0; j < cnt; ++j) {
            int   sj = __shfl(s,  j, 64);
            float b0 = __shfl(a0, j, 64);
            float b1 = __shfl(a1, j, 64);
            float b2 = __shfl(a2, j, 64);
            float b3 = __shfl(a3, j, 64);
            const float* xp = xl + (size_t)sj * 256 + lane;
            acc0 = fmaf(b0, xp[0],   acc0);
            acc1 = fmaf(b1, xp[64],  acc1);
            acc2 = fmaf(b2, xp[128], acc2);
            acc3 = fmaf(b3, xp[192], acc3);
        }
    }

    // epilogue: mean over heads + bias, LayerNorm over 64 channels, ELU, residual
    float o = (acc0 + acc1 + acc2 + acc3) * 0.25f + gat_b[lane];
    float mu = o;
    for (int off = 32; off; off >>= 1) mu += __shfl_xor(mu, off, 64);
    mu *= (1.f / 64.f);
    float dz = o - mu;
    float var = dz * dz;
    for (int off = 32; off; off >>= 1) var += __shfl_xor(var, off, 64);
    var *= (1.f / 64.f);
    float v = dz * rsqrtf(var + LN_EPS) * ln_g[lane] + ln_b[lane];
    v = v > 0.f ? v : (__expf(v) - 1.f);
    if (use_res) v += h_res[(size_t)d * HID + lane];
    h_out[(size_t)d * HID + lane] = v;
}

// ---------------- final GEMM: out = h @ Wo + bo, Wo [64,40] ----------------

__global__ __launch_bounds__(256) void k_gemm_out(const float* __restrict__ h,
                                                  const float* __restrict__ Wo,
                                                  const float* __restrict__ bo,
                                                  float* __restrict__ out) {
    __shared__ float Ws[HID * OUT_CH];   // 10 KB
    __shared__ float hs[6 * HID];
    int tid = threadIdx.x;
    int row0 = blockIdx.x * 6;
    for (int i = tid; i < HID * OUT_CH; i += 256) Ws[i] = Wo[i];
    for (int i = tid; i < 6 * HID; i += 256) {
        int r = row0 + (i >> 6);
        hs[i] = (r < N_NODES) ? h[(size_t)r * HID + (i & 63)] : 0.f;
    }
    __syncthreads();
    if (tid < 240) {
        int r = tid / 40, o = tid - r * 40;
        int rr = row0 + r;
        if (rr < N_NODES) {
            float acc = bo[o];
            for (int k = 0; k < HID; ++k)
                acc = fmaf(hs[r * HID + k], Ws[k * OUT_CH + o], acc);
            out[(size_t)row0 * OUT_CH + tid] = acc;
        }
    }
}

// ---------------- launch ----------------

extern "C" void kernel_launch(void* const* d_in, const int* in_sizes, int n_in,
                              void* d_out, int out_size, void* d_ws, size_t ws_size,
                              hipStream_t stream) {
    const float* x       = (const float*)d_in[0];
    const int*   ei      = (const int*)  d_in[1];
    const float* Wi      = (const float*)d_in[2];
    const float* bi      = (const float*)d_in[3];
    const float* lin_W   = (const float*)d_in[4];
    const float* att_src = (const float*)d_in[5];
    const float* att_dst = (const float*)d_in[6];
    const float* gat_b   = (const float*)d_in[7];
    const float* ln_g    = (const float*)d_in[8];
    const float* ln_b    = (const float*)d_in[9];
    const float* Wo      = (const float*)d_in[10];
    const float* bo      = (const float*)d_in[11];
    float* out = (float*)d_out;

    char* ws = (char*)d_ws;
    size_t off = 0;
    auto alloc = [&](size_t bytes) -> void* {
        void* p = ws + off;
        off += (bytes + 255) & ~(size_t)255;
        return p;
    };
    float* h_a     = (float*)alloc((size_t)N_NODES * HID * 4);
    float* h_b     = (float*)alloc((size_t)N_NODES * HID * 4);
    float* xl      = (float*)alloc((size_t)N_NODES * 256 * 4);
    float* alpha_s = (float*)alloc((size_t)N_NODES * 4 * 4);
    float* alpha_d = (float*)alloc((size_t)N_NODES * 4 * 4);
    int*   cnt     = (int*)  alloc((size_t)N_NODES * 4);
    int*   cursor  = (int*)  alloc((size_t)N_NODES * 4);
    int*   row_ptr = (int*)  alloc((size_t)(N_NODES + 1) * 4);
    int*   csr_src = (int*)  alloc((size_t)E_TOT * 4);

    // CSR build
    hipMemsetAsync(cnt, 0, (size_t)N_NODES * 4, stream);
    int egrid = (E_TOT + 255) / 256;
    k_hist<<<egrid, 256, 0, stream>>>(ei, cnt);
    k_scan<<<1, 1024, 0, stream>>>(cnt, row_ptr, cursor);
    k_scatter<<<egrid, 256, 0, stream>>>(ei, cursor, csr_src);

    // input projection
    int rtiles = (N_NODES + 63) / 64;
    k_gemm_in<<<rtiles, 256, 0, stream>>>(x, Wi, bi, h_a);

    float* h_cur = h_a;
    float* h_nxt = h_b;
    int ngrid4 = N_NODES / 4;   // 12500
    for (int l = 0; l < LAYERS; ++l) {
        k_gemm_xl<<<rtiles, 256, 0, stream>>>(h_cur, lin_W + (size_t)l * HID * 256, xl);
        k_alpha<<<ngrid4, 256, 0, stream>>>(xl, att_src + (size_t)l * 256,
                                            att_dst + (size_t)l * 256, alpha_s, alpha_d);
        k_aggregate<<<ngrid4, 256, 0, stream>>>(xl, alpha_s, alpha_d, row_ptr, csr_src,
                                                gat_b + (size_t)l * HID,
                                                ln_g + (size_t)l * HID,
                                                ln_b + (size_t)l * HID,
                                                h_cur, h_nxt, l > 0 ? 1 : 0);
        float* t = h_cur; h_cur = h_nxt; h_nxt = t;
    }

    int ogrid = (N_NODES + 5) / 6;
    k_gemm_out<<<ogrid, 256, 0, stream>>>(h_cur, Wo, bo, out);
}

// Round 2
// 828.389 us; speedup vs baseline: 1.4094x; 1.4094x over previous
//
#include <hip/hip_runtime.h>
#include <hip/hip_bf16.h>

#define N_NODES 50000
#define N_EDGES 800000
#define E_TOT   (N_EDGES + N_NODES)   // 850000 with self-loops
#define IN_CH   128
#define HID     64
#define HEADS   4
#define OUT_CH  40
#define LAYERS  4
#define LN_EPS  1e-5f

__device__ __forceinline__ unsigned short f2bf(float f) {
    unsigned u = __float_as_uint(f);
    unsigned r = (u + 0x7fffu + ((u >> 16) & 1u)) >> 16;   // RNE
    return (unsigned short)r;
}
__device__ __forceinline__ float bf_lo(unsigned u) { return __uint_as_float(u << 16); }
__device__ __forceinline__ float bf_hi(unsigned u) { return __uint_as_float(u & 0xffff0000u); }

// ---------------- CSR build (dst -> list of src), rebuilt every launch ----------------

__global__ void k_hist(const int* __restrict__ ei, int* __restrict__ cnt) {
    int e = blockIdx.x * blockDim.x + threadIdx.x;
    if (e >= E_TOT) return;
    int dst = (e < N_EDGES) ? ei[N_EDGES + e] : (e - N_EDGES);
    atomicAdd(&cnt[dst], 1);
}

__global__ __launch_bounds__(1024) void k_scan(const int* __restrict__ cnt,
                                               int* __restrict__ row_ptr,
                                               int* __restrict__ cursor) {
    __shared__ int wave_tot[16];
    __shared__ int s_carry;
    int tid = threadIdx.x, lane = tid & 63, w = tid >> 6;
    if (tid == 0) s_carry = 0;
    __syncthreads();
    for (int base = 0; base < N_NODES; base += 1024) {
        int i = base + tid;
        int v = (i < N_NODES) ? cnt[i] : 0;
        int x = v;
        for (int off = 1; off < 64; off <<= 1) {
            int t = __shfl_up(x, off, 64);
            if (lane >= off) x += t;
        }
        if (lane == 63) wave_tot[w] = x;
        __syncthreads();
        if (w == 0) {
            int t = (lane < 16) ? wave_tot[lane] : 0;
            for (int off = 1; off < 16; off <<= 1) {
                int u = __shfl_up(t, off, 64);
                if (lane >= off) t += u;
            }
            if (lane < 16) wave_tot[lane] = t;
        }
        __syncthreads();
        int wave_off = (w > 0) ? wave_tot[w - 1] : 0;
        int excl = s_carry + wave_off + x - v;
        if (i < N_NODES) { row_ptr[i] = excl; cursor[i] = excl; }
        __syncthreads();
        if (tid == 0) s_carry += wave_tot[15];
        __syncthreads();
    }
    if (threadIdx.x == 0) row_ptr[N_NODES] = s_carry;
}

__global__ void k_scatter(const int* __restrict__ ei, int* __restrict__ cursor,
                          int* __restrict__ csr_src) {
    int e = blockIdx.x * blockDim.x + threadIdx.x;
    if (e >= E_TOT) return;
    int src, dst;
    if (e < N_EDGES) { src = ei[e]; dst = ei[N_EDGES + e]; }
    else             { src = dst = e - N_EDGES; }
    int pos = atomicAdd(&cursor[dst], 1);
    csr_src[pos] = src;
}

// ---------------- layer-0 GEMM: h = elu(x @ Wi + bi); register-tiled 4x4 ----------------
// tile: 64 rows x 64 cols per block, 256 threads

__global__ __launch_bounds__(256) void k_gemm_in(const float* __restrict__ x,
                                                 const float* __restrict__ Wi,
                                                 const float* __restrict__ bi,
                                                 float* __restrict__ h) {
    __shared__ float xT[IN_CH * 64];   // [k][row] 32 KB
    __shared__ float Ws[IN_CH * HID];  // [k][col] 32 KB
    int tid = threadIdx.x;
    int row0 = blockIdx.x * 64;
    for (int i = tid * 4; i < IN_CH * HID; i += 1024)
        *(float4*)(Ws + i) = *(const float4*)(Wi + i);
    {
        int r = tid >> 2, k0 = (tid & 3) * 32;
        int rr = row0 + r;
#pragma unroll
        for (int j = 0; j < 32; j += 4) {
            float4 v = (rr < N_NODES) ? *(const float4*)(x + (size_t)rr * IN_CH + k0 + j)
                                      : make_float4(0.f, 0.f, 0.f, 0.f);
            xT[(k0 + j    ) * 64 + r] = v.x;
            xT[(k0 + j + 1) * 64 + r] = v.y;
            xT[(k0 + j + 2) * 64 + r] = v.z;
            xT[(k0 + j + 3) * 64 + r] = v.w;
        }
    }
    __syncthreads();
    int tx = tid & 15, ty = tid >> 4;
    int c0 = tx * 4, r0 = ty * 4;
    float acc[4][4] = {};
    for (int k = 0; k < IN_CH; ++k) {
        float4 xv = *(const float4*)(xT + k * 64 + r0);
        float4 wv = *(const float4*)(Ws + k * HID + c0);
        float xr[4] = {xv.x, xv.y, xv.z, xv.w};
        float wc[4] = {wv.x, wv.y, wv.z, wv.w};
#pragma unroll
        for (int r = 0; r < 4; ++r)
#pragma unroll
            for (int c = 0; c < 4; ++c)
                acc[r][c] = fmaf(xr[r], wc[c], acc[r][c]);
    }
    float4 bv = *(const float4*)(bi + c0);
    float bcs[4] = {bv.x, bv.y, bv.z, bv.w};
#pragma unroll
    for (int r = 0; r < 4; ++r) {
        int rr = row0 + r0 + r;
        if (rr < N_NODES) {
            float4 o;
            float t0 = acc[r][0] + bcs[0]; o.x = t0 > 0.f ? t0 : (__expf(t0) - 1.f);
            float t1 = acc[r][1] + bcs[1]; o.y = t1 > 0.f ? t1 : (__expf(t1) - 1.f);
            float t2 = acc[r][2] + bcs[2]; o.z = t2 > 0.f ? t2 : (__expf(t2) - 1.f);
            float t3 = acc[r][3] + bcs[3]; o.w = t3 > 0.f ? t3 : (__expf(t3) - 1.f);
            *(float4*)(h + (size_t)rr * HID + c0) = o;
        }
    }
}

// ---------------- per-layer GEMM: xl = h @ W  (fp32 compute, bf16 output) ----------------
// tile: 64 rows x 256 cols per block, 256 threads, 8x8 per thread

__global__ __launch_bounds__(256) void k_gemm_xl(const float* __restrict__ h,
                                                 const float* __restrict__ W,
                                                 unsigned short* __restrict__ xl) {
    __shared__ float Ws[HID * 256];   // [k][c] 64 KB
    __shared__ float hT[HID * 64];    // [k][row] 16 KB
    int tid = threadIdx.x;
    int row0 = blockIdx.x * 64;
    for (int i = tid * 4; i < HID * 256; i += 1024)
        *(float4*)(Ws + i) = *(const float4*)(W + i);
    {
        int r = tid >> 2, k0 = (tid & 3) * 16;
        int rr = row0 + r;
#pragma unroll
        for (int j = 0; j < 16; j += 4) {
            float4 v = (rr < N_NODES) ? *(const float4*)(h + (size_t)rr * HID + k0 + j)
                                      : make_float4(0.f, 0.f, 0.f, 0.f);
            hT[(k0 + j    ) * 64 + r] = v.x;
            hT[(k0 + j + 1) * 64 + r] = v.y;
            hT[(k0 + j + 2) * 64 + r] = v.z;
            hT[(k0 + j + 3) * 64 + r] = v.w;
        }
    }
    __syncthreads();
    int tx = tid & 31, ty = tid >> 5;
    int c0 = tx * 8, r0 = ty * 8;
    float acc[8][8] = {};
    for (int k = 0; k < HID; ++k) {
        float4 hA = *(const float4*)(hT + k * 64 + r0);
        float4 hB = *(const float4*)(hT + k * 64 + r0 + 4);
        float4 wA = *(const float4*)(Ws + k * 256 + c0);
        float4 wB = *(const float4*)(Ws + k * 256 + c0 + 4);
        float hr[8] = {hA.x, hA.y, hA.z, hA.w, hB.x, hB.y, hB.z, hB.w};
        float wc[8] = {wA.x, wA.y, wA.z, wA.w, wB.x, wB.y, wB.z, wB.w};
#pragma unroll
        for (int r = 0; r < 8; ++r)
#pragma unroll
            for (int c = 0; c < 8; ++c)
                acc[r][c] = fmaf(hr[r], wc[c], acc[r][c]);
    }
#pragma unroll
    for (int r = 0; r < 8; ++r) {
        int rr = row0 + r0 + r;
        if (rr < N_NODES) {
            unsigned short tmp[8];
#pragma unroll
            for (int c = 0; c < 8; ++c) tmp[c] = f2bf(acc[r][c]);
            *(uint4*)(xl + (size_t)rr * 256 + c0) = *(uint4*)tmp;
        }
    }
}

// ---------------- alpha_s/alpha_d from bf16 xl ----------------

__global__ __launch_bounds__(256) void k_alpha(const unsigned short* __restrict__ xl,
                                               const float* __restrict__ a_src,  // [4,64]
                                               const float* __restrict__ a_dst,
                                               float* __restrict__ alpha_s,
                                               float* __restrict__ alpha_d) {
    int lane = threadIdx.x & 63;
    int n = blockIdx.x * 4 + (threadIdx.x >> 6);
    if (n >= N_NODES) return;
    uint2 u = *(const uint2*)(xl + (size_t)n * 256 + lane * 4);
    float f0 = bf_lo(u.x), f1 = bf_hi(u.x), f2 = bf_lo(u.y), f3 = bf_hi(u.y);
    int hh = lane >> 4;
    int c0 = (lane & 15) * 4;
    float4 as = *(const float4*)(a_src + hh * HID + c0);
    float4 ad = *(const float4*)(a_dst + hh * HID + c0);
    float ps = f0 * as.x + f1 * as.y + f2 * as.z + f3 * as.w;
    float pd = f0 * ad.x + f1 * ad.y + f2 * ad.z + f3 * ad.w;
    for (int off = 1; off < 16; off <<= 1) {
        ps += __shfl_xor(ps, off, 64);
        pd += __shfl_xor(pd, off, 64);
    }
    if ((lane & 15) == 0) {
        alpha_s[n * 4 + hh] = ps;
        alpha_d[n * 4 + hh] = pd;
    }
}

// ---------------- fused GAT aggregate + mean-heads + bias + LN + ELU + residual ----------------
// one wave per dst node; lane holds 4 channels (cg*4..cg*4+3) of head hh

__device__ __forceinline__ void edge_scores(float4 as, float4 ad,
                                            float& s0, float& s1, float& s2, float& s3) {
    s0 = as.x + ad.x; s0 = s0 > 0.f ? s0 : 0.2f * s0;
    s1 = as.y + ad.y; s1 = s1 > 0.f ? s1 : 0.2f * s1;
    s2 = as.z + ad.z; s2 = s2 > 0.f ? s2 : 0.2f * s2;
    s3 = as.w + ad.w; s3 = s3 > 0.f ? s3 : 0.2f * s3;
}

__global__ __launch_bounds__(256) void k_aggregate(
    const unsigned short* __restrict__ xl,   // bf16 [N][256] head-major
    const float* __restrict__ alpha_s,
    const float* __restrict__ alpha_d,
    const int* __restrict__ row_ptr,
    const int* __restrict__ csr_src,
    const float* __restrict__ gat_b,
    const float* __restrict__ ln_g,
    const float* __restrict__ ln_b,
    const float* __restrict__ h_res,
    float* __restrict__ h_out,
    int use_res)
{
    int lane = threadIdx.x & 63;
    int d = blockIdx.x * 4 + (threadIdx.x >> 6);
    if (d >= N_NODES) return;
    int start = row_ptr[d], end = row_ptr[d + 1];

    float4 ad = *(const float4*)(alpha_d + d * 4);

    // pass 1: segment max per head
    float m0 = -1e30f, m1 = -1e30f, m2 = -1e30f, m3 = -1e30f;
    for (int base = start; base < end; base += 64) {
        int idx = base + lane;
        if (idx < end) {
            int s = csr_src[idx];
            float4 as = *(const float4*)(alpha_s + s * 4);
            float s0, s1, s2, s3; edge_scores(as, ad, s0, s1, s2, s3);
            m0 = fmaxf(m0, s0); m1 = fmaxf(m1, s1);
            m2 = fmaxf(m2, s2); m3 = fmaxf(m3, s3);
        }
    }
    for (int off = 32; off; off >>= 1) {
        m0 = fmaxf(m0, __shfl_xor(m0, off, 64));
        m1 = fmaxf(m1, __shfl_xor(m1, off, 64));
        m2 = fmaxf(m2, __shfl_xor(m2, off, 64));
        m3 = fmaxf(m3, __shfl_xor(m3, off, 64));
    }

    // pass 2: denom
    float d0 = 0.f, d1 = 0.f, d2 = 0.f, d3 = 0.f;
    for (int base = start; base < end; base += 64) {
        int idx = base + lane;
        if (idx < end) {
            int s = csr_src[idx];
            float4 as = *(const float4*)(alpha_s + s * 4);
            float s0, s1, s2, s3; edge_scores(as, ad, s0, s1, s2, s3);
            d0 += __expf(s0 - m0); d1 += __expf(s1 - m1);
            d2 += __expf(s2 - m2); d3 += __expf(s3 - m3);
        }
    }
    for (int off = 32; off; off >>= 1) {
        d0 += __shfl_xor(d0, off, 64);
        d1 += __shfl_xor(d1, off, 64);
        d2 += __shfl_xor(d2, off, 64);
        d3 += __shfl_xor(d3, off, 64);
    }
    float i0 = 1.f / (d0 + 1e-16f), i1 = 1.f / (d1 + 1e-16f);
    float i2 = 1.f / (d2 + 1e-16f), i3 = 1.f / (d3 + 1e-16f);

    // pass 3: weighted gather-accumulate; lane owns 4 channels of one head
    int hh = lane >> 4;
    int cg = lane & 15;
    float acc0 = 0.f, acc1 = 0.f, acc2 = 0.f, acc3 = 0.f;
    for (int base = start; base < end; base += 64) {
        int cnt = min(64, end - base);
        int s = 0; float a0 = 0.f, a1 = 0.f, a2 = 0.f, a3 = 0.f;
        if (lane < cnt) {
            s = csr_src[base + lane];
            float4 as = *(const float4*)(alpha_s + s * 4);
            float s0, s1, s2, s3; edge_scores(as, ad, s0, s1, s2, s3);
            a0 = __expf(s0 - m0) * i0; a1 = __expf(s1 - m1) * i1;
            a2 = __expf(s2 - m2) * i2; a3 = __expf(s3 - m3) * i3;
        }
        for (int j = 0; j < cnt; ++j) {
            int   sj = __shfl(s,  j, 64);
            float b0 = __shfl(a0, j, 64);
            float b1 = __shfl(a1, j, 64);
            float b2 = __shfl(a2, j, 64);
            float b3 = __shfl(a3, j, 64);
            float w = (hh == 0) ? b0 : (hh == 1) ? b1 : (hh == 2) ? b2 : b3;
            uint2 u = *(const uint2*)(xl + (size_t)sj * 256 + lane * 4);  // 4 bf16
            acc0 = fmaf(w, bf_lo(u.x), acc0);
            acc1 = fmaf(w, bf_hi(u.x), acc1);
            acc2 = fmaf(w, bf_lo(u.y), acc2);
            acc3 = fmaf(w, bf_hi(u.y), acc3);
        }
    }

    // mean over heads: lanes {cg, cg+16, cg+32, cg+48} hold same channels
    acc0 += __shfl_xor(acc0, 16, 64); acc0 += __shfl_xor(acc0, 32, 64);
    acc1 += __shfl_xor(acc1, 16, 64); acc1 += __shfl_xor(acc1, 32, 64);
    acc2 += __shfl_xor(acc2, 16, 64); acc2 += __shfl_xor(acc2, 32, 64);
    acc3 += __shfl_xor(acc3, 16, 64); acc3 += __shfl_xor(acc3, 32, 64);

    int c0 = cg * 4;
    float4 gb = *(const float4*)(gat_b + c0);
    float o0 = acc0 * 0.25f + gb.x;
    float o1 = acc1 * 0.25f + gb.y;
    float o2 = acc2 * 0.25f + gb.z;
    float o3 = acc3 * 0.25f + gb.w;

    // LayerNorm over 64 channels (reduce within each 16-lane replica group)
    float mu = o0 + o1 + o2 + o3;
    for (int off = 1; off < 16; off <<= 1) mu += __shfl_xor(mu, off, 64);
    mu *= (1.f / 64.f);
    float z0 = o0 - mu, z1 = o1 - mu, z2 = o2 - mu, z3 = o3 - mu;
    float var = z0 * z0 + z1 * z1 + z2 * z2 + z3 * z3;
    for (int off = 1; off < 16; off <<= 1) var += __shfl_xor(var, off, 64);
    var *= (1.f / 64.f);
    float rstd = rsqrtf(var + LN_EPS);

    float4 g  = *(const float4*)(ln_g + c0);
    float4 bb = *(const float4*)(ln_b + c0);
    float v0 = z0 * rstd * g.x + bb.x; v0 = v0 > 0.f ? v0 : (__expf(v0) - 1.f);
    float v1 = z1 * rstd * g.y + bb.y; v1 = v1 > 0.f ? v1 : (__expf(v1) - 1.f);
    float v2 = z2 * rstd * g.z + bb.z; v2 = v2 > 0.f ? v2 : (__expf(v2) - 1.f);
    float v3 = z3 * rstd * g.w + bb.w; v3 = v3 > 0.f ? v3 : (__expf(v3) - 1.f);

    if (hh == 0) {
        float4 o;
        if (use_res) {
            float4 r = *(const float4*)(h_res + (size_t)d * HID + c0);
            o.x = v0 + r.x; o.y = v1 + r.y; o.z = v2 + r.z; o.w = v3 + r.w;
        } else {
            o.x = v0; o.y = v1; o.z = v2; o.w = v3;
        }
        *(float4*)(h_out + (size_t)d * HID + c0) = o;
    }
}

// ---------------- final GEMM: out = h @ Wo + bo, Wo [64,40] ----------------

__global__ __launch_bounds__(256) void k_gemm_out(const float* __restrict__ h,
                                                  const float* __restrict__ Wo,
                                                  const float* __restrict__ bo,
                                                  float* __restrict__ out) {
    __shared__ float Ws[HID * OUT_CH];   // 10 KB
    __shared__ float hs[6 * HID];
    int tid = threadIdx.x;
    int row0 = blockIdx.x * 6;
    for (int i = tid; i < HID * OUT_CH; i += 256) Ws[i] = Wo[i];
    for (int i = tid; i < 6 * HID; i += 256) {
        int r = row0 + (i >> 6);
        hs[i] = (r < N_NODES) ? h[(size_t)r * HID + (i & 63)] : 0.f;
    }
    __syncthreads();
    if (tid < 240) {
        int r = tid / 40, o = tid - r * 40;
        int rr = row0 + r;
        if (rr < N_NODES) {
            float acc = bo[o];
            for (int k = 0; k < HID; ++k)
                acc = fmaf(hs[r * HID + k], Ws[k * OUT_CH + o], acc);
            out[(size_t)row0 * OUT_CH + tid] = acc;
        }
    }
}

// ---------------- launch ----------------

extern "C" void kernel_launch(void* const* d_in, const int* in_sizes, int n_in,
                              void* d_out, int out_size, void* d_ws, size_t ws_size,
                              hipStream_t stream) {
    const float* x       = (const float*)d_in[0];
    const int*   ei      = (const int*)  d_in[1];
    const float* Wi      = (const float*)d_in[2];
    const float* bi      = (const float*)d_in[3];
    const float* lin_W   = (const float*)d_in[4];
    const float* att_src = (const float*)d_in[5];
    const float* att_dst = (const float*)d_in[6];
    const float* gat_b   = (const float*)d_in[7];
    const float* ln_g    = (const float*)d_in[8];
    const float* ln_b    = (const float*)d_in[9];
    const float* Wo      = (const float*)d_in[10];
    const float* bo      = (const float*)d_in[11];
    float* out = (float*)d_out;

    char* ws = (char*)d_ws;
    size_t off = 0;
    auto alloc = [&](size_t bytes) -> void* {
        void* p = ws + off;
        off += (bytes + 255) & ~(size_t)255;
        return p;
    };
    float*          h_a     = (float*)alloc((size_t)N_NODES * HID * 4);
    float*          h_b     = (float*)alloc((size_t)N_NODES * HID * 4);
    unsigned short* xl      = (unsigned short*)alloc((size_t)N_NODES * 256 * 2);
    float*          alpha_s = (float*)alloc((size_t)N_NODES * 4 * 4);
    float*          alpha_d = (float*)alloc((size_t)N_NODES * 4 * 4);
    int*            cnt     = (int*)  alloc((size_t)N_NODES * 4);
    int*            cursor  = (int*)  alloc((size_t)N_NODES * 4);
    int*            row_ptr = (int*)  alloc((size_t)(N_NODES + 1) * 4);
    int*            csr_src = (int*)  alloc((size_t)E_TOT * 4);

    // CSR build
    hipMemsetAsync(cnt, 0, (size_t)N_NODES * 4, stream);
    int egrid = (E_TOT + 255) / 256;
    k_hist<<<egrid, 256, 0, stream>>>(ei, cnt);
    k_scan<<<1, 1024, 0, stream>>>(cnt, row_ptr, cursor);
    k_scatter<<<egrid, 256, 0, stream>>>(ei, cursor, csr_src);

    // input projection
    int rtiles = (N_NODES + 63) / 64;
    k_gemm_in<<<rtiles, 256, 0, stream>>>(x, Wi, bi, h_a);

    float* h_cur = h_a;
    float* h_nxt = h_b;
    int ngrid4 = N_NODES / 4;   // 12500
    for (int l = 0; l < LAYERS; ++l) {
        k_gemm_xl<<<rtiles, 256, 0, stream>>>(h_cur, lin_W + (size_t)l * HID * 256, xl);
        k_alpha<<<ngrid4, 256, 0, stream>>>(xl, att_src + (size_t)l * 256,
                                            att_dst + (size_t)l * 256, alpha_s, alpha_d);
        k_aggregate<<<ngrid4, 256, 0, stream>>>(xl, alpha_s, alpha_d, row_ptr, csr_src,
                                                gat_b + (size_t)l * HID,
                                                ln_g + (size_t)l * HID,
                                                ln_b + (size_t)l * HID,
                                                h_cur, h_nxt, l > 0 ? 1 : 0);
        float* t = h_cur; h_cur = h_nxt; h_nxt = t;
    }

    int ogrid = (N_NODES + 5) / 6;
    k_gemm_out<<<ogrid, 256, 0, stream>>>(h_cur, Wo, bo, out);
}

// Round 3
// 740.579 us; speedup vs baseline: 1.5765x; 1.1186x over previous
//
#include <hip/hip_runtime.h>
#include <hip/hip_bf16.h>

#define N_NODES 50000
#define N_EDGES 800000
#define E_TOT   (N_EDGES + N_NODES)   // 850000 with self-loops
#define IN_CH   128
#define HID     64
#define HEADS   4
#define OUT_CH  40
#define LAYERS  4
#define LN_EPS  1e-5f

__device__ __forceinline__ unsigned short f2bf(float f) {
    unsigned u = __float_as_uint(f);
    unsigned r = (u + 0x7fffu + ((u >> 16) & 1u)) >> 16;   // RNE
    return (unsigned short)r;
}
__device__ __forceinline__ float bf_lo(unsigned u) { return __uint_as_float(u << 16); }
__device__ __forceinline__ float bf_hi(unsigned u) { return __uint_as_float(u & 0xffff0000u); }
__device__ __forceinline__ float lrelu(float x) { return x > 0.f ? x : 0.2f * x; }

// order-preserving float<->uint encoding for atomicMax on floats
__device__ __forceinline__ unsigned fenc(float f) {
    unsigned u = __float_as_uint(f);
    return (u & 0x80000000u) ? ~u : (u | 0x80000000u);
}
__device__ __forceinline__ float fdec(unsigned k) {
    unsigned u = (k & 0x80000000u) ? (k & 0x7fffffffu) : ~k;
    return __uint_as_float(u);
}

// ---------------- CSR build (dst -> list of src), rebuilt every launch ----------------

__global__ void k_hist(const int* __restrict__ ei, int* __restrict__ cnt) {
    int e = blockIdx.x * blockDim.x + threadIdx.x;
    if (e >= E_TOT) return;
    int dst = (e < N_EDGES) ? ei[N_EDGES + e] : (e - N_EDGES);
    atomicAdd(&cnt[dst], 1);
}

// 3-phase scan: A) per-block local exclusive scan, B) scan block sums, C) add offsets
__global__ __launch_bounds__(1024) void k_scan_a(const int* __restrict__ cnt,
                                                 int* __restrict__ row_ptr,
                                                 int* __restrict__ bsum) {
    __shared__ int wt[16];
    int tid = threadIdx.x, lane = tid & 63, w = tid >> 6;
    int i = blockIdx.x * 1024 + tid;
    int v = (i < N_NODES) ? cnt[i] : 0;
    int x = v;
    for (int off = 1; off < 64; off <<= 1) {
        int t = __shfl_up(x, off, 64);
        if (lane >= off) x += t;
    }
    if (lane == 63) wt[w] = x;
    __syncthreads();
    if (w == 0) {
        int t = (lane < 16) ? wt[lane] : 0;
        for (int off = 1; off < 16; off <<= 1) {
            int u = __shfl_up(t, off, 64);
            if (lane >= off) t += u;
        }
        if (lane < 16) wt[lane] = t;
    }
    __syncthreads();
    int woff = (w > 0) ? wt[w - 1] : 0;
    if (i < N_NODES) row_ptr[i] = woff + x - v;
    if (tid == 0) bsum[blockIdx.x] = wt[15];
}

#define SCAN_BLOCKS 49   // ceil(50000/1024)

__global__ __launch_bounds__(64) void k_scan_b(const int* __restrict__ bsum,
                                               int* __restrict__ boff,
                                               int* __restrict__ row_ptr) {
    int lane = threadIdx.x;
    int v = (lane < SCAN_BLOCKS) ? bsum[lane] : 0;
    int x = v;
    for (int off = 1; off < 64; off <<= 1) {
        int t = __shfl_up(x, off, 64);
        if (lane >= off) x += t;
    }
    if (lane < SCAN_BLOCKS) boff[lane] = x - v;       // exclusive
    if (lane == 63) row_ptr[N_NODES] = x;             // total
}

__global__ __launch_bounds__(256) void k_scan_c(int* __restrict__ row_ptr,
                                                int* __restrict__ cursor,
                                                const int* __restrict__ boff) {
    int i = blockIdx.x * 256 + threadIdx.x;
    if (i >= N_NODES) return;
    int r = row_ptr[i] + boff[i >> 10];
    row_ptr[i] = r;
    cursor[i] = r;
}

__global__ void k_scatter(const int* __restrict__ ei, int* __restrict__ cursor,
                          int* __restrict__ csr_src) {
    int e = blockIdx.x * blockDim.x + threadIdx.x;
    if (e >= E_TOT) return;
    int src, dst;
    if (e < N_EDGES) { src = ei[e]; dst = ei[N_EDGES + e]; }
    else             { src = dst = e - N_EDGES; }
    int pos = atomicAdd(&cursor[dst], 1);
    csr_src[pos] = src;
}

// ---------------- layer-0 GEMM: h = elu(x @ Wi + bi); register-tiled 4x4 ----------------

__global__ __launch_bounds__(256) void k_gemm_in(const float* __restrict__ x,
                                                 const float* __restrict__ Wi,
                                                 const float* __restrict__ bi,
                                                 float* __restrict__ h) {
    __shared__ float xT[IN_CH * 64];   // [k][row]
    __shared__ float Ws[IN_CH * HID];  // [k][col]
    int tid = threadIdx.x;
    int row0 = blockIdx.x * 64;
    for (int i = tid * 4; i < IN_CH * HID; i += 1024)
        *(float4*)(Ws + i) = *(const float4*)(Wi + i);
    {
        int r = tid >> 2, k0 = (tid & 3) * 32;
        int rr = row0 + r;
#pragma unroll
        for (int j = 0; j < 32; j += 4) {
            float4 v = (rr < N_NODES) ? *(const float4*)(x + (size_t)rr * IN_CH + k0 + j)
                                      : make_float4(0.f, 0.f, 0.f, 0.f);
            xT[(k0 + j    ) * 64 + r] = v.x;
            xT[(k0 + j + 1) * 64 + r] = v.y;
            xT[(k0 + j + 2) * 64 + r] = v.z;
            xT[(k0 + j + 3) * 64 + r] = v.w;
        }
    }
    __syncthreads();
    int tx = tid & 15, ty = tid >> 4;
    int c0 = tx * 4, r0 = ty * 4;
    float acc[4][4] = {};
    for (int k = 0; k < IN_CH; ++k) {
        float4 xv = *(const float4*)(xT + k * 64 + r0);
        float4 wv = *(const float4*)(Ws + k * HID + c0);
        float xr[4] = {xv.x, xv.y, xv.z, xv.w};
        float wc[4] = {wv.x, wv.y, wv.z, wv.w};
#pragma unroll
        for (int r = 0; r < 4; ++r)
#pragma unroll
            for (int c = 0; c < 4; ++c)
                acc[r][c] = fmaf(xr[r], wc[c], acc[r][c]);
    }
    float4 bv = *(const float4*)(bi + c0);
    float bcs[4] = {bv.x, bv.y, bv.z, bv.w};
#pragma unroll
    for (int r = 0; r < 4; ++r) {
        int rr = row0 + r0 + r;
        if (rr < N_NODES) {
            float4 o;
            float t0 = acc[r][0] + bcs[0]; o.x = t0 > 0.f ? t0 : (__expf(t0) - 1.f);
            float t1 = acc[r][1] + bcs[1]; o.y = t1 > 0.f ? t1 : (__expf(t1) - 1.f);
            float t2 = acc[r][2] + bcs[2]; o.z = t2 > 0.f ? t2 : (__expf(t2) - 1.f);
            float t3 = acc[r][3] + bcs[3]; o.w = t3 > 0.f ? t3 : (__expf(t3) - 1.f);
            *(float4*)(h + (size_t)rr * HID + c0) = o;
        }
    }
}

// ---------------- per-layer GEMM: xl = h @ W (bf16 out) + fused alpha + global head-max ----------------
// tile: 64 rows x 256 cols, 256 threads, 8x8 per thread

__global__ __launch_bounds__(256) void k_gemm_xl(const float* __restrict__ h,
                                                 const float* __restrict__ W,
                                                 const float* __restrict__ a_src,  // [4][64]
                                                 const float* __restrict__ a_dst,
                                                 unsigned short* __restrict__ xl,
                                                 float* __restrict__ alpha_s,
                                                 float* __restrict__ alpha_d,
                                                 unsigned* __restrict__ mxk) {    // [4]
    __shared__ float Ws[HID * 256];   // [k][c]
    __shared__ float hT[HID * 64];    // [k][row]
    __shared__ unsigned s_mx[4];
    int tid = threadIdx.x;
    int row0 = blockIdx.x * 64;
    if (tid < 4) s_mx[tid] = 0;
    for (int i = tid * 4; i < HID * 256; i += 1024)
        *(float4*)(Ws + i) = *(const float4*)(W + i);
    {
        int r = tid >> 2, k0 = (tid & 3) * 16;
        int rr = row0 + r;
#pragma unroll
        for (int j = 0; j < 16; j += 4) {
            float4 v = (rr < N_NODES) ? *(const float4*)(h + (size_t)rr * HID + k0 + j)
                                      : make_float4(0.f, 0.f, 0.f, 0.f);
            hT[(k0 + j    ) * 64 + r] = v.x;
            hT[(k0 + j + 1) * 64 + r] = v.y;
            hT[(k0 + j + 2) * 64 + r] = v.z;
            hT[(k0 + j + 3) * 64 + r] = v.w;
        }
    }
    __syncthreads();
    int tx = tid & 31, ty = tid >> 5;
    int c0 = tx * 8, r0 = ty * 8;
    float acc[8][8] = {};
    for (int k = 0; k < HID; ++k) {
        float4 hA = *(const float4*)(hT + k * 64 + r0);
        float4 hB = *(const float4*)(hT + k * 64 + r0 + 4);
        float4 wA = *(const float4*)(Ws + k * 256 + c0);
        float4 wB = *(const float4*)(Ws + k * 256 + c0 + 4);
        float hr[8] = {hA.x, hA.y, hA.z, hA.w, hB.x, hB.y, hB.z, hB.w};
        float wc[8] = {wA.x, wA.y, wA.z, wA.w, wB.x, wB.y, wB.z, wB.w};
#pragma unroll
        for (int r = 0; r < 8; ++r)
#pragma unroll
            for (int c = 0; c < 8; ++c)
                acc[r][c] = fmaf(hr[r], wc[c], acc[r][c]);
    }
#pragma unroll
    for (int r = 0; r < 8; ++r) {
        int rr = row0 + r0 + r;
        if (rr < N_NODES) {
            unsigned short tmp[8];
#pragma unroll
            for (int c = 0; c < 8; ++c) tmp[c] = f2bf(acc[r][c]);
            *(uint4*)(xl + (size_t)rr * 256 + c0) = *(uint4*)tmp;
        }
    }
    // fused alpha: cols c0..c0+7 all belong to head tx>>3, channels (tx&7)*8..+7
    int head = tx >> 3, qq = tx & 7;
    const float* ap = a_src + head * HID + qq * 8;
    const float* dp = a_dst + head * HID + qq * 8;
    float4 aA = *(const float4*)(ap),     aB = *(const float4*)(ap + 4);
    float4 dA = *(const float4*)(dp),     dB = *(const float4*)(dp + 4);
    float pmax = -1e30f;
#pragma unroll
    for (int r = 0; r < 8; ++r) {
        float ps = acc[r][0] * aA.x + acc[r][1] * aA.y + acc[r][2] * aA.z + acc[r][3] * aA.w
                 + acc[r][4] * aB.x + acc[r][5] * aB.y + acc[r][6] * aB.z + acc[r][7] * aB.w;
        float pd = acc[r][0] * dA.x + acc[r][1] * dA.y + acc[r][2] * dA.z + acc[r][3] * dA.w
                 + acc[r][4] * dB.x + acc[r][5] * dB.y + acc[r][6] * dB.z + acc[r][7] * dB.w;
#pragma unroll
        for (int off = 1; off < 8; off <<= 1) {
            ps += __shfl_xor(ps, off, 64);
            pd += __shfl_xor(pd, off, 64);
        }
        if (qq == 0) {
            int rr = row0 + r0 + r;
            if (rr < N_NODES) {
                alpha_s[rr * 4 + head] = ps;
                alpha_d[rr * 4 + head] = pd;
                pmax = fmaxf(pmax, ps);
            }
        }
    }
    if (qq == 0) atomicMax(&s_mx[head], fenc(pmax));
    __syncthreads();
    if (tid < 4) atomicMax(&mxk[tid], s_mx[tid]);
}

// ---------------- fused single-sweep GAT aggregate + mean-heads + bias + LN + ELU + residual ----
// one wave per dst node; lane m=lane&31 owns 8 bf16 cols m*8..m*8+7 (head m>>3);
// halves (lane>>5) process even/odd edges

__global__ __launch_bounds__(256) void k_aggregate(
    const unsigned short* __restrict__ xl,   // bf16 [N][256]
    const float* __restrict__ alpha_s,
    const float* __restrict__ alpha_d,
    const int* __restrict__ row_ptr,
    const int* __restrict__ csr_src,
    const unsigned* __restrict__ mxk,        // [4]
    const float* __restrict__ gat_b,
    const float* __restrict__ ln_g,
    const float* __restrict__ ln_b,
    const float* __restrict__ h_res,
    float* __restrict__ h_out,
    int use_res)
{
    __shared__ int    s_lds[4][64];
    __shared__ float4 w_lds[4][64];
    __shared__ int    s_nch[4];
    int tid = threadIdx.x, lane = tid & 63, wv = tid >> 6;
    int d = blockIdx.x * 4 + wv;             // grid exactly covers N/4
    int start = row_ptr[d], end = row_ptr[d + 1];

    float4 ad = *(const float4*)(alpha_d + d * 4);
    float mp0 = lrelu(fdec(mxk[0]) + ad.x);
    float mp1 = lrelu(fdec(mxk[1]) + ad.y);
    float mp2 = lrelu(fdec(mxk[2]) + ad.z);
    float mp3 = lrelu(fdec(mxk[3]) + ad.w);

    int nch = (end - start + 63) >> 6;
    if (lane == 0) s_nch[wv] = nch;
    __syncthreads();
    int C = max(max(s_nch[0], s_nch[1]), max(s_nch[2], s_nch[3]));

    int half = lane >> 5, m = lane & 31, hq = m >> 3, q = m & 7;
    float acc[8] = {};
    float ds0 = 0.f, ds1 = 0.f, ds2 = 0.f, ds3 = 0.f;

    for (int ch = 0; ch < C; ++ch) {
        int base = start + (ch << 6);
        int cnt = end - base; cnt = cnt < 0 ? 0 : (cnt > 64 ? 64 : cnt);
        int s = 0;
        float w0 = 0.f, w1 = 0.f, w2 = 0.f, w3 = 0.f;
        if (lane < cnt) {
            s = csr_src[base + lane];
            float4 as = *(const float4*)(alpha_s + s * 4);
            w0 = __expf(lrelu(as.x + ad.x) - mp0);
            w1 = __expf(lrelu(as.y + ad.y) - mp1);
            w2 = __expf(lrelu(as.z + ad.z) - mp2);
            w3 = __expf(lrelu(as.w + ad.w) - mp3);
        }
        ds0 += w0; ds1 += w1; ds2 += w2; ds3 += w3;
        s_lds[wv][lane] = s;
        w_lds[wv][lane] = make_float4(w0, w1, w2, w3);
        __syncthreads();
        int iters = (cnt + 1) >> 1;
        for (int jj = 0; jj < iters; ++jj) {
            int e = (jj << 1) + half;
            int sj = s_lds[wv][e];
            float w = ((const float*)&w_lds[wv][e])[hq];
            uint4 u = *(const uint4*)(xl + ((size_t)sj << 8) + (m << 3));
            acc[0] = fmaf(w, bf_lo(u.x), acc[0]);
            acc[1] = fmaf(w, bf_hi(u.x), acc[1]);
            acc[2] = fmaf(w, bf_lo(u.y), acc[2]);
            acc[3] = fmaf(w, bf_hi(u.y), acc[3]);
            acc[4] = fmaf(w, bf_lo(u.z), acc[4]);
            acc[5] = fmaf(w, bf_hi(u.z), acc[5]);
            acc[6] = fmaf(w, bf_lo(u.w), acc[6]);
            acc[7] = fmaf(w, bf_hi(u.w), acc[7]);
        }
        __syncthreads();
    }

    // combine halves (even/odd edges of same dst)
#pragma unroll
    for (int k = 0; k < 8; ++k) acc[k] += __shfl_xor(acc[k], 32, 64);

    // denominators: full-wave sum
    for (int off = 1; off < 64; off <<= 1) {
        ds0 += __shfl_xor(ds0, off, 64);
        ds1 += __shfl_xor(ds1, off, 64);
        ds2 += __shfl_xor(ds2, off, 64);
        ds3 += __shfl_xor(ds3, off, 64);
    }
    float dsel = (hq == 0) ? ds0 : (hq == 1) ? ds1 : (hq == 2) ? ds2 : ds3;
    float inv = 1.f / (dsel + 1e-16f);
#pragma unroll
    for (int k = 0; k < 8; ++k) acc[k] *= inv;

    // mean over heads: lanes m, m^8, m^16, m^24 hold heads 0..3 of channels q*8..+7
#pragma unroll
    for (int k = 0; k < 8; ++k) {
        acc[k] += __shfl_xor(acc[k], 8, 64);
        acc[k] += __shfl_xor(acc[k], 16, 64);
    }
    float4 gbA = *(const float4*)(gat_b + q * 8);
    float4 gbB = *(const float4*)(gat_b + q * 8 + 4);
    float o[8];
    o[0] = acc[0] * 0.25f + gbA.x; o[1] = acc[1] * 0.25f + gbA.y;
    o[2] = acc[2] * 0.25f + gbA.z; o[3] = acc[3] * 0.25f + gbA.w;
    o[4] = acc[4] * 0.25f + gbB.x; o[5] = acc[5] * 0.25f + gbB.y;
    o[6] = acc[6] * 0.25f + gbB.z; o[7] = acc[7] * 0.25f + gbB.w;

    // LayerNorm over 64 channels: sum across q octet (xor 1,2,4)
    float sl = o[0] + o[1] + o[2] + o[3] + o[4] + o[5] + o[6] + o[7];
    for (int off = 1; off < 8; off <<= 1) sl += __shfl_xor(sl, off, 64);
    float mu = sl * (1.f / 64.f);
    float vl = 0.f;
#pragma unroll
    for (int k = 0; k < 8; ++k) { float z = o[k] - mu; vl += z * z; }
    for (int off = 1; off < 8; off <<= 1) vl += __shfl_xor(vl, off, 64);
    float rstd = rsqrtf(vl * (1.f / 64.f) + LN_EPS);

    if (lane < 8) {   // q = lane, hq = 0, half = 0 — unique channel owners
        float4 gA = *(const float4*)(ln_g + q * 8);
        float4 gB = *(const float4*)(ln_g + q * 8 + 4);
        float4 bA = *(const float4*)(ln_b + q * 8);
        float4 bB = *(const float4*)(ln_b + q * 8 + 4);
        float gg[8] = {gA.x, gA.y, gA.z, gA.w, gB.x, gB.y, gB.z, gB.w};
        float bb[8] = {bA.x, bA.y, bA.z, bA.w, bB.x, bB.y, bB.z, bB.w};
        float v[8];
#pragma unroll
        for (int k = 0; k < 8; ++k) {
            float t = (o[k] - mu) * rstd * gg[k] + bb[k];
            v[k] = t > 0.f ? t : (__expf(t) - 1.f);
        }
        if (use_res) {
            float4 rA = *(const float4*)(h_res + (size_t)d * HID + q * 8);
            float4 rB = *(const float4*)(h_res + (size_t)d * HID + q * 8 + 4);
            v[0] += rA.x; v[1] += rA.y; v[2] += rA.z; v[3] += rA.w;
            v[4] += rB.x; v[5] += rB.y; v[6] += rB.z; v[7] += rB.w;
        }
        *(float4*)(h_out + (size_t)d * HID + q * 8)     = make_float4(v[0], v[1], v[2], v[3]);
        *(float4*)(h_out + (size_t)d * HID + q * 8 + 4) = make_float4(v[4], v[5], v[6], v[7]);
    }
}

// ---------------- final GEMM: out = h @ Wo + bo, Wo [64,40] ----------------

__global__ __launch_bounds__(256) void k_gemm_out(const float* __restrict__ h,
                                                  const float* __restrict__ Wo,
                                                  const float* __restrict__ bo,
                                                  float* __restrict__ out) {
    __shared__ float Ws[HID * OUT_CH];
    __shared__ float hs[6 * HID];
    int tid = threadIdx.x;
    int row0 = blockIdx.x * 6;
    for (int i = tid; i < HID * OUT_CH; i += 256) Ws[i] = Wo[i];
    for (int i = tid; i < 6 * HID; i += 256) {
        int r = row0 + (i >> 6);
        hs[i] = (r < N_NODES) ? h[(size_t)r * HID + (i & 63)] : 0.f;
    }
    __syncthreads();
    if (tid < 240) {
        int r = tid / 40, o = tid - r * 40;
        int rr = row0 + r;
        if (rr < N_NODES) {
            float acc = bo[o];
            for (int k = 0; k < HID; ++k)
                acc = fmaf(hs[r * HID + k], Ws[k * OUT_CH + o], acc);
            out[(size_t)row0 * OUT_CH + tid] = acc;
        }
    }
}

// ---------------- launch ----------------

extern "C" void kernel_launch(void* const* d_in, const int* in_sizes, int n_in,
                              void* d_out, int out_size, void* d_ws, size_t ws_size,
                              hipStream_t stream) {
    const float* x       = (const float*)d_in[0];
    const int*   ei      = (const int*)  d_in[1];
    const float* Wi      = (const float*)d_in[2];
    const float* bi      = (const float*)d_in[3];
    const float* lin_W   = (const float*)d_in[4];
    const float* att_src = (const float*)d_in[5];
    const float* att_dst = (const float*)d_in[6];
    const float* gat_b   = (const float*)d_in[7];
    const float* ln_g    = (const float*)d_in[8];
    const float* ln_b    = (const float*)d_in[9];
    const float* Wo      = (const float*)d_in[10];
    const float* bo      = (const float*)d_in[11];
    float* out = (float*)d_out;

    char* ws = (char*)d_ws;
    size_t off = 0;
    auto alloc = [&](size_t bytes) -> void* {
        void* p = ws + off;
        off += (bytes + 255) & ~(size_t)255;
        return p;
    };
    float*          h_a     = (float*)alloc((size_t)N_NODES * HID * 4);
    float*          h_b     = (float*)alloc((size_t)N_NODES * HID * 4);
    unsigned short* xl      = (unsigned short*)alloc((size_t)N_NODES * 256 * 2);
    float*          alpha_s = (float*)alloc((size_t)N_NODES * 4 * 4);
    float*          alpha_d = (float*)alloc((size_t)N_NODES * 4 * 4);
    int*            cnt     = (int*)  alloc((size_t)N_NODES * 4);
    int*            cursor  = (int*)  alloc((size_t)N_NODES * 4);
    int*            row_ptr = (int*)  alloc((size_t)(N_NODES + 1) * 4);
    int*            csr_src = (int*)  alloc((size_t)E_TOT * 4);
    unsigned*       maxkey  = (unsigned*)alloc((size_t)LAYERS * 4 * 4);
    int*            bsum    = (int*)  alloc((size_t)SCAN_BLOCKS * 4);
    int*            boff    = (int*)  alloc((size_t)SCAN_BLOCKS * 4);

    hipMemsetAsync(cnt, 0, (size_t)N_NODES * 4, stream);
    hipMemsetAsync(maxkey, 0, (size_t)LAYERS * 4 * 4, stream);

    int egrid = (E_TOT + 255) / 256;
    k_hist<<<egrid, 256, 0, stream>>>(ei, cnt);
    k_scan_a<<<SCAN_BLOCKS, 1024, 0, stream>>>(cnt, row_ptr, bsum);
    k_scan_b<<<1, 64, 0, stream>>>(bsum, boff, row_ptr);
    k_scan_c<<<(N_NODES + 255) / 256, 256, 0, stream>>>(row_ptr, cursor, boff);
    k_scatter<<<egrid, 256, 0, stream>>>(ei, cursor, csr_src);

    int rtiles = (N_NODES + 63) / 64;
    k_gemm_in<<<rtiles, 256, 0, stream>>>(x, Wi, bi, h_a);

    float* h_cur = h_a;
    float* h_nxt = h_b;
    int ngrid4 = N_NODES / 4;   // 12500
    for (int l = 0; l < LAYERS; ++l) {
        k_gemm_xl<<<rtiles, 256, 0, stream>>>(h_cur, lin_W + (size_t)l * HID * 256,
                                              att_src + (size_t)l * 256,
                                              att_dst + (size_t)l * 256,
                                              xl, alpha_s, alpha_d, maxkey + l * 4);
        k_aggregate<<<ngrid4, 256, 0, stream>>>(xl, alpha_s, alpha_d, row_ptr, csr_src,
                                                maxkey + l * 4,
                                                gat_b + (size_t)l * HID,
                                                ln_g + (size_t)l * HID,
                                                ln_b + (size_t)l * HID,
                                                h_cur, h_nxt, l > 0 ? 1 : 0);
        float* t = h_cur; h_cur = h_nxt; h_nxt = t;
    }

    int ogrid = (N_NODES + 5) / 6;
    k_gemm_out<<<ogrid, 256, 0, stream>>>(h_cur, Wo, bo, out);
}